// Round 5
// baseline (1486.210 us; speedup 1.0000x reference)
//
#include <hip/hip_runtime.h>
#include <hip/hip_bf16.h>
#include <stdint.h>

#define NN   100000   // nodes per type
#define EE   600000   // edges per type
#define HH   128      // hidden
#define OUTC 64       // out channels

typedef __attribute__((ext_vector_type(8))) short bf16x8;   // 8 bf16 in 4 VGPRs
typedef __attribute__((ext_vector_type(4))) float f32x4;

__device__ __forceinline__ float bfbits2f(unsigned short b) {
    union { unsigned u; float f; } v; v.u = ((unsigned)b) << 16; return v.f;
}
__device__ __forceinline__ unsigned short f2bfbits(float f) {
    union { float f; unsigned u; } v; v.f = f;
    unsigned r = v.u + 0x7fffu + ((v.u >> 16) & 1u);   // RNE
    return (unsigned short)(r >> 16);
}

// ---------------------------------------------------------------------------
__global__ __launch_bounds__(256) void cvt_f32_bf16(
    const float* __restrict__ in, unsigned short* __restrict__ out, int n)
{
    int i = blockIdx.x * 256 + threadIdx.x;
    if (i < n) out[i] = f2bfbits(in[i]);
}

// out = bf16(a + b)  — used to merge the two root-weight matrices (x@WrA+x@WrB)
__global__ __launch_bounds__(256) void wsum_f32_bf16(
    const float* __restrict__ a, const float* __restrict__ b,
    unsigned short* __restrict__ out, int n)
{
    int i = blockIdx.x * 256 + threadIdx.x;
    if (i < n) out[i] = f2bfbits(a[i] + b[i]);
}

// ---------------------------------------------------------------------------
// Linked-list adjacency build, all 4 edge types in one pass.
// node writes coalesced; head is a 1.6 MB L2-resident atomicExch region.
// ---------------------------------------------------------------------------
__global__ __launch_bounds__(256) void build_ll(
    const int* __restrict__ ei0, const int* __restrict__ ei1,
    const int* __restrict__ ei2, const int* __restrict__ ei3,
    int* __restrict__ head,      // [4*NN], pre-init to -1
    int2* __restrict__ node)     // [4*EE]
{
    int gid = blockIdx.x * 256 + threadIdx.x;
    if (gid >= 4 * EE) return;
    int t = gid / EE, e = gid - t * EE;
    const int* ei = (t == 0) ? ei0 : (t == 1) ? ei1 : (t == 2) ? ei2 : ei3;
    int src = ei[e];
    int dst = ei[EE + e];
    int prev = atomicExch(&head[t * NN + dst], gid);
    node[gid] = make_int2(src, prev);
}

// ---------------------------------------------------------------------------
// Gather-mean via linked-list traversal: one wave per dst row.
// ---------------------------------------------------------------------------
template<bool SRCF32>
__global__ __launch_bounds__(256) void gather_ll(
    const int* __restrict__ head,    // head + t*NN
    const int2* __restrict__ node,
    const void* __restrict__ xsrc_,  // [NN*HH] fp32 or bf16
    unsigned* __restrict__ out)      // [NN*HH/2] packed bf16x2, normalized
{
    int w    = (blockIdx.x * 256 + threadIdx.x) >> 6;
    int lane = threadIdx.x & 63;
    if (w >= NN) return;
    int e = head[w];
    float ax = 0.f, ay = 0.f;
    int cnt = 0;
    while (e >= 0) {
        int2 n = node[e];          // (src, next) — one dependent 8B load/hop
        if (SRCF32) {
            float2 v = ((const float2*)((const float*)xsrc_ + (size_t)n.x * HH))[lane];
            ax += v.x; ay += v.y;
        } else {
            unsigned v = ((const unsigned*)((const unsigned short*)xsrc_ + (size_t)n.x * HH))[lane];
            ax += bfbits2f((unsigned short)(v & 0xffffu));
            ay += bfbits2f((unsigned short)(v >> 16));
        }
        ++cnt;
        e = n.y;
    }
    float inv = 1.0f / fmaxf((float)cnt, 1.0f);
    unsigned lo = f2bfbits(ax * inv);
    unsigned hi = f2bfbits(ay * inv);
    out[(size_t)w * 64 + lane] = (hi << 16) | lo;
}

// ---------------------------------------------------------------------------
// SAGE GEMM + fused LN/ReLU/residual epilogue.
//   TWOAGG=0: C = aggA @ WlA^T + X @ Wr^T + blA
//   TWOAGG=1: C = aggA @ WlA^T + aggB @ WlB^T + X @ Wr^T + (blA+blB), Wr merged
//   out = relu(LN(scale*C; g,b)) + X     (scale=0.5 when TWOAGG)
// Wave = 4 row-tiles x 128 cols = 64 rows; block = 4 waves = 256 rows.
// Each B fragment load feeds 4 independent MFMAs (amortize VMEM latency).
// ---------------------------------------------------------------------------
template<bool TWOAGG, bool XF32>
__global__ __launch_bounds__(256, 2) void sage_gemm(
    const unsigned short* __restrict__ agg16A,
    const unsigned short* __restrict__ WlA, const float* __restrict__ blA,
    const unsigned short* __restrict__ agg16B,
    const unsigned short* __restrict__ WlB, const float* __restrict__ blB,
    const void* __restrict__ X,       // root features = residual source
    const unsigned short* __restrict__ Wr,   // merged when TWOAGG
    const float* __restrict__ g, const float* __restrict__ bt,
    unsigned short* __restrict__ out)
{
    const int lane = threadIdx.x & 63;
    const int wid  = threadIdx.x >> 6;
    const int m    = lane & 15;
    const int q    = lane >> 4;
    const int rowbase = blockIdx.x * 256 + wid * 64;

    int arow[4];
    for (int t = 0; t < 4; ++t) {
        int r = rowbase + t * 16 + m;
        arow[t] = (r < NN) ? r : (NN - 1);      // clamp loads; stores guarded
    }

    f32x4 acc[4][8];
    for (int t = 0; t < 4; ++t)
        for (int ct = 0; ct < 8; ++ct) acc[t][ct] = (f32x4){0.f, 0.f, 0.f, 0.f};

    for (int ks = 0; ks < 4; ++ks) {
        const int k0 = ks * 32 + q * 8;
        bf16x8 aR[4], aA[4], aB[4];
        for (int t = 0; t < 4; ++t) {
            if (XF32) {
                f32x4 r0 = *(const f32x4*)((const float*)X + (size_t)arow[t] * HH + k0);
                f32x4 r1 = *(const f32x4*)((const float*)X + (size_t)arow[t] * HH + k0 + 4);
                aR[t][0] = (short)f2bfbits(r0[0]); aR[t][1] = (short)f2bfbits(r0[1]);
                aR[t][2] = (short)f2bfbits(r0[2]); aR[t][3] = (short)f2bfbits(r0[3]);
                aR[t][4] = (short)f2bfbits(r1[0]); aR[t][5] = (short)f2bfbits(r1[1]);
                aR[t][6] = (short)f2bfbits(r1[2]); aR[t][7] = (short)f2bfbits(r1[3]);
            } else {
                aR[t] = *(const bf16x8*)((const unsigned short*)X + (size_t)arow[t] * HH + k0);
            }
            aA[t] = *(const bf16x8*)(agg16A + (size_t)arow[t] * HH + k0);
            if (TWOAGG)
                aB[t] = *(const bf16x8*)(agg16B + (size_t)arow[t] * HH + k0);
        }
        for (int ct = 0; ct < 8; ++ct) {
            const size_t wb = (size_t)((ct * 16 + m) * HH + k0);
            bf16x8 bWl = *(const bf16x8*)(WlA + wb);
            bf16x8 bWr = *(const bf16x8*)(Wr  + wb);
            bf16x8 bWl2;
            if (TWOAGG) bWl2 = *(const bf16x8*)(WlB + wb);
            for (int t = 0; t < 4; ++t)
                acc[t][ct] = __builtin_amdgcn_mfma_f32_16x16x32_bf16(aA[t], bWl, acc[t][ct], 0, 0, 0);
            for (int t = 0; t < 4; ++t)
                acc[t][ct] = __builtin_amdgcn_mfma_f32_16x16x32_bf16(aR[t], bWr, acc[t][ct], 0, 0, 0);
            if (TWOAGG)
                for (int t = 0; t < 4; ++t)
                    acc[t][ct] = __builtin_amdgcn_mfma_f32_16x16x32_bf16(aB[t], bWl2, acc[t][ct], 0, 0, 0);
        }
    }

    // -------- epilogue: bias -> (x0.5 if s) -> LN -> relu -> +residual --------
    const float scale = TWOAGG ? 0.5f : 1.0f;
    float bias[8], gam[8], bet[8];
    for (int ct = 0; ct < 8; ++ct) {
        int j = ct * 16 + m;
        float bb = blA[j];
        if (TWOAGG) bb += blB[j];
        bias[ct] = bb;
        gam[ct]  = g[j];
        bet[ct]  = bt[j];
    }
    for (int t = 0; t < 4; ++t) {
        float mu[4], rstd[4];
        for (int r = 0; r < 4; ++r) {
            float p = 0.f, p2 = 0.f;
            for (int ct = 0; ct < 8; ++ct) {
                float c = (acc[t][ct][r] + bias[ct]) * scale;
                acc[t][ct][r] = c;
                p += c; p2 += c * c;
            }
            for (int off = 1; off < 16; off <<= 1) {
                p  += __shfl_xor(p,  off);
                p2 += __shfl_xor(p2, off);
            }
            float mean = p * (1.0f / 128.0f);
            float var  = p2 * (1.0f / 128.0f) - mean * mean;
            mu[r]   = mean;
            rstd[r] = rsqrtf(var + 1e-5f);
        }
        for (int r = 0; r < 4; ++r) {
            int i = rowbase + t * 16 + q * 4 + r;
            if (i >= NN) continue;
            for (int ct = 0; ct < 8; ++ct) {
                int j = ct * 16 + m;
                float v = (acc[t][ct][r] - mu[r]) * rstd[r] * gam[ct] + bet[ct];
                v = fmaxf(v, 0.f);
                float res = XF32 ? ((const float*)X)[(size_t)i * HH + j]
                                 : bfbits2f(((const unsigned short*)X)[(size_t)i * HH + j]);
                out[(size_t)i * HH + j] = f2bfbits(v + res);
            }
        }
    }
}

// ---------------------------------------------------------------------------
// Final projection: out = X @ Wout^T + bout   (NN x 64), fp32 output
// ---------------------------------------------------------------------------
__global__ __launch_bounds__(256) void final_proj(
    const unsigned short* __restrict__ X, const unsigned short* __restrict__ W,
    const float* __restrict__ bias, float* __restrict__ out)
{
    const int lane = threadIdx.x & 63;
    const int wid  = threadIdx.x >> 6;
    const int m    = lane & 15;
    const int q    = lane >> 4;
    const int row0 = blockIdx.x * 64 + wid * 16;
    int arow = row0 + m;
    if (arow >= NN) arow = NN - 1;

    f32x4 acc[4];
    for (int ct = 0; ct < 4; ++ct) acc[ct] = (f32x4){0.f, 0.f, 0.f, 0.f};

    for (int ks = 0; ks < 4; ++ks) {
        const int k0 = ks * 32 + q * 8;
        bf16x8 aR = *(const bf16x8*)(X + (size_t)arow * HH + k0);
        for (int ct = 0; ct < 4; ++ct) {
            const size_t wb = (size_t)((ct * 16 + m) * HH + k0);
            acc[ct] = __builtin_amdgcn_mfma_f32_16x16x32_bf16(
                aR, *(const bf16x8*)(W + wb), acc[ct], 0, 0, 0);
        }
    }
    for (int r = 0; r < 4; ++r) {
        int i = row0 + q * 4 + r;
        if (i >= NN) continue;
        for (int ct = 0; ct < 4; ++ct) {
            int j = ct * 16 + m;
            out[(size_t)i * OUTC + j] = acc[ct][r] + bias[j];
        }
    }
}

// ---------------------------------------------------------------------------
extern "C" void kernel_launch(void* const* d_in, const int* in_sizes, int n_in,
                              void* d_out, int out_size, void* d_ws, size_t ws_size,
                              hipStream_t stream)
{
    const float* xs  = (const float*)d_in[0];
    const float* xo  = (const float*)d_in[1];
    const float* xf  = (const float*)d_in[2];
    const int* ei0 = (const int*)d_in[3];
    const int* ei1 = (const int*)d_in[4];
    const int* ei2 = (const int*)d_in[5];
    const int* ei3 = (const int*)d_in[6];
    const float* Wl1 = (const float*)d_in[7];
    const float* bl1 = (const float*)d_in[8];
    const float* Wr1 = (const float*)d_in[9];
    const float* Wl2 = (const float*)d_in[10];
    const float* bl2 = (const float*)d_in[11];
    const float* Wr2 = (const float*)d_in[12];
    const float* lng = (const float*)d_in[13];
    const float* lnb = (const float*)d_in[14];
    const float* Wou = (const float*)d_in[15];
    const float* bou = (const float*)d_in[16];
    float* out = (float*)d_out;

    // workspace layout (16B aligned)
    char* ws = (char*)d_ws;
    const size_t xBytes = (size_t)NN * HH * 2;     // 25.6 MB (bf16)
    const int    WH     = HH * HH;                 // 16384
    unsigned short* aggA16 = (unsigned short*)ws; ws += xBytes;
    unsigned short* aggB16 = (unsigned short*)ws; ws += xBytes;
    unsigned short* s1 = (unsigned short*)ws;     ws += xBytes;
    unsigned short* o1 = (unsigned short*)ws;     ws += xBytes;
    unsigned short* f1 = (unsigned short*)ws;     ws += xBytes;
    int*  head = (int*)ws;  ws += (size_t)4 * NN * 4;   // 1.6 MB
    int2* node = (int2*)ws; ws += (size_t)4 * EE * 8;   // 19.2 MB
    unsigned short* Wl1b = (unsigned short*)ws; ws += (size_t)4 * WH * 2;
    unsigned short* Wr1b = (unsigned short*)ws; ws += (size_t)4 * WH * 2;
    unsigned short* Wl2b = (unsigned short*)ws; ws += (size_t)4 * WH * 2;
    unsigned short* WrS1 = (unsigned short*)ws; ws += (size_t)WH * 2;  // Wr1[1]+Wr1[3]
    unsigned short* WrS2 = (unsigned short*)ws; ws += (size_t)WH * 2;  // Wr2[1]+Wr2[3]
    unsigned short* Woub = (unsigned short*)ws; ws += (size_t)OUTC * HH * 2;
    unsigned short* s2 = o1;   // o1 dead once layer-2 gathers are done

    const int egrid = (4 * EE + 255) / 256;   // build
    const int ngrid = (NN * 64 + 255) / 256;  // gather: 1 wave per node
    const int ggrid = (NN + 255) / 256;       // gemm: 256 rows per block
    const int pgrid = (NN + 63) / 64;         // final_proj: 64 rows per block

    // ---- weights -> bf16 (reused 100k x); merged root weights for study ----
    cvt_f32_bf16<<<(4 * WH + 255) / 256, 256, 0, stream>>>(Wl1, Wl1b, 4 * WH);
    cvt_f32_bf16<<<(4 * WH + 255) / 256, 256, 0, stream>>>(Wr1, Wr1b, 4 * WH);
    cvt_f32_bf16<<<(4 * WH + 255) / 256, 256, 0, stream>>>(Wl2, Wl2b, 4 * WH);
    wsum_f32_bf16<<<(WH + 255) / 256, 256, 0, stream>>>(Wr1 + 1 * WH, Wr1 + 3 * WH, WrS1, WH);
    wsum_f32_bf16<<<(WH + 255) / 256, 256, 0, stream>>>(Wr2 + 1 * WH, Wr2 + 3 * WH, WrS2, WH);
    cvt_f32_bf16<<<(OUTC * HH + 255) / 256, 256, 0, stream>>>(Wou, Woub, OUTC * HH);

    // ---- adjacency build (all 4 edge types) ----
    hipMemsetAsync(head, 0xFF, (size_t)4 * NN * 4, stream);   // head = -1
    build_ll<<<egrid, 256, 0, stream>>>(ei0, ei1, ei2, ei3, head, node);

    // ---- layer 1: type 0 (study->outcome) -> o1 ----
    gather_ll<true><<<ngrid, 256, 0, stream>>>(head + 0 * NN, node, xs, (unsigned*)aggA16);
    sage_gemm<false, true><<<ggrid, 256, 0, stream>>>(aggA16, Wl1b + 0 * WH, bl1 + 0 * HH,
        nullptr, nullptr, nullptr,
        xo, Wr1b + 0 * WH, lng, lnb, o1);

    // ---- layer 1: type 2 (study->facility) -> f1 ----
    gather_ll<true><<<ngrid, 256, 0, stream>>>(head + 2 * NN, node, xs, (unsigned*)aggA16);
    sage_gemm<false, true><<<ggrid, 256, 0, stream>>>(aggA16, Wl1b + 2 * WH, bl1 + 2 * HH,
        nullptr, nullptr, nullptr,
        xf, Wr1b + 2 * WH, lng, lnb, f1);

    // ---- layer 1: types 1,3 (outcome->study, facility->study) -> s1 ----
    gather_ll<true><<<ngrid, 256, 0, stream>>>(head + 1 * NN, node, xo, (unsigned*)aggA16);
    gather_ll<true><<<ngrid, 256, 0, stream>>>(head + 3 * NN, node, xf, (unsigned*)aggB16);
    sage_gemm<true, true><<<ggrid, 256, 0, stream>>>(aggA16, Wl1b + 1 * WH, bl1 + 1 * HH,
        aggB16, Wl1b + 3 * WH, bl1 + 3 * HH,
        xs, WrS1, lng, lnb, s1);

    // ---- layer 2: only the study output feeds the final projection ----
    gather_ll<false><<<ngrid, 256, 0, stream>>>(head + 1 * NN, node, o1, (unsigned*)aggA16);
    gather_ll<false><<<ngrid, 256, 0, stream>>>(head + 3 * NN, node, f1, (unsigned*)aggB16);
    sage_gemm<true, false><<<ggrid, 256, 0, stream>>>(aggA16, Wl2b + 1 * WH, bl2 + 1 * HH,
        aggB16, Wl2b + 3 * WH, bl2 + 3 * HH,
        s1, WrS2, lng + HH, lnb + HH, s2);

    // ---- final projection (fp32 out) ----
    final_proj<<<pgrid, 256, 0, stream>>>(s2, Woub, bou, out);
}